// Round 2
// baseline (481.854 us; speedup 1.0000x reference)
//
#include <hip/hip_runtime.h>

// Problem constants (from reference)
constexpr int V = 96, K = 20, D = 1024, B = 256;
constexpr int E_DIM = 4, N_DIM = 2, C_DIM = 2;
constexpr int VK = V * K;                  // 1920 floats per (i,j,e,n,c,b) slab
constexpr int ENC = E_DIM * N_DIM * C_DIM; // 16
constexpr int NIJ = 9;
constexpr int BCH = 16;                    // b-samples per main-pass block
constexpr int NBC = B / BCH;               // 16
constexpr int NSLOTS = 256;                // fp64 accumulator slots

// ---------------------------------------------------------------------------
// 1) Fused Y reduction + missing-rate. One block per d (128 threads).
//    Also zeroes the fp64 accumulator slots (block 0) - safe because nothing
//    atomically accumulates until main_kernel, which is stream-ordered later.
__global__ __launch_bounds__(128) void ymr_kernel(const float* __restrict__ Y,
                                                  float* __restrict__ mr,
                                                  double* __restrict__ acc) {
    const int d = blockIdx.x;
    const int tid = threadIdx.x;
    if (d == 0) { acc[tid] = 0.0; acc[tid + 128] = 0.0; }

    const float4* __restrict__ base = (const float4*)Y;
    float a[NIJ];
#pragma unroll
    for (int ij = 0; ij < NIJ; ++ij) {
        float s = 0.f;
#pragma unroll
        for (int it = 0; it < 3; ++it) {
            int idx = tid + it * 128;          // [0,384): enc-major, 24 float4/row
            int enc = idx / 24, v4 = idx % 24;
            size_t off4 = ((size_t)(ij * ENC + enc) * D + d) * 24 + v4;
            float4 y = base[off4];
            s += y.x + y.y + y.z + y.w;
        }
        a[ij] = s;
    }
    __shared__ float Rw[2][NIJ];
    const int lane = tid & 63, wv = tid >> 6;
#pragma unroll
    for (int ij = 0; ij < NIJ; ++ij) {
        float s = a[ij];
#pragma unroll
        for (int off = 32; off; off >>= 1) s += __shfl_down(s, off, 64);
        if (lane == 0) Rw[wv][ij] = s;
    }
    __syncthreads();
    if (tid == 0) {
        float y[NIJ], tot = 0.f;
#pragma unroll
        for (int ij = 0; ij < NIJ; ++ij) { y[ij] = Rw[0][ij] + Rw[1][ij]; tot += y[ij]; }
        mr[0 * D + d] = (y[0] + y[1] + y[3] + y[4]) / tot;  // m00
        mr[1 * D + d] = (y[2] + y[5]) / tot;                // m01 (r missing)
        mr[2 * D + d] = (y[6] + y[7]) / tot;                // m10 (t missing)
        mr[3 * D + d] = y[8] / tot;                         // m11
    }
}

// ---------------------------------------------------------------------------
// 2) Factor tables, all in LOG domain:
//    LT[ij][v][k]  = log(T[ij,v,k])                      (9*1920)
//    LH[ij][enc][k]= log(qt*qr*pe*pn*pc)                 (9*16*20)
//    LM[ij][b]     = log(mr3[i,j, index[b]])             (9*256)
__global__ __launch_bounds__(256) void factors_kernel(
    const float* __restrict__ T0_, const float* __restrict__ t_,
    const float* __restrict__ r_, const float* __restrict__ e_,
    const float* __restrict__ n_, const float* __restrict__ c_,
    const float* __restrict__ mr, const int* __restrict__ index,
    float* __restrict__ LT, float* __restrict__ LH, float* __restrict__ LM) {
    __shared__ float T0s[VK], lts[VK], lrs[VK];
    __shared__ float pt[K], pr[K];
    __shared__ float pes[E_DIM * K], pns[N_DIM * K], pcs[C_DIM * K];
    const int tid = threadIdx.x;

    for (int idx = tid; idx < VK; idx += 256) {
        lts[idx] = 1.0f / (1.0f + expf(-t_[idx]));
        lrs[idx] = 1.0f / (1.0f + expf(-r_[idx]));
    }
    if (tid < K) {  // T0 = softmax(_T0, axis=0) per column k
        const int k = tid;
        float mx = -1e30f;
        for (int v = 0; v < V; ++v) mx = fmaxf(mx, T0_[v * K + k]);
        float ssum = 0.f;
        for (int v = 0; v < V; ++v) {
            float ev = expf(T0_[v * K + k] - mx);
            T0s[v * K + k] = ev; ssum += ev;
        }
        for (int v = 0; v < V; ++v) T0s[v * K + k] /= ssum;
    }
    __syncthreads();

    if (tid < K) {
        const int k = tid;
        float spt = 0.f, spr = 0.f;
        for (int v = 0; v < V; ++v) {
            spt += T0s[v * K + k] * lts[v * K + k];
            spr += T0s[v * K + k] * lrs[v * K + k];
        }
        pt[k] = spt; pr[k] = spr;
        {   // pe: softmax over E_DIM=4
            float m = -1e30f;
            for (int e2 = 0; e2 < E_DIM; ++e2) m = fmaxf(m, e_[e2 * K + k]);
            float se = 0.f; float tmp[E_DIM];
            for (int e2 = 0; e2 < E_DIM; ++e2) { tmp[e2] = expf(e_[e2 * K + k] - m); se += tmp[e2]; }
            for (int e2 = 0; e2 < E_DIM; ++e2) pes[e2 * K + k] = tmp[e2] / se;
        }
        {   // pn
            float m = fmaxf(n_[k], n_[K + k]);
            float a0 = expf(n_[k] - m), a1 = expf(n_[K + k] - m);
            pns[k] = a0 / (a0 + a1); pns[K + k] = a1 / (a0 + a1);
        }
        {   // pc
            float m = fmaxf(c_[k], c_[K + k]);
            float a0 = expf(c_[k] - m), a1 = expf(c_[K + k] - m);
            pcs[k] = a0 / (a0 + a1); pcs[K + k] = a1 / (a0 + a1);
        }
    }
    __syncthreads();

    // LT[ij][v][k]
    for (int id = tid; id < NIJ * K; id += 256) {
        const int k = id % K;
        const int ij = id / K;
        const int i = ij / 3, j = ij % 3;
        float ssum = 0.f;
        for (int v = 0; v < V; ++v) {
            float lt = lts[v * K + k], lr = lrs[v * K + k];
            float wt = (i == 0) ? lt : (i == 1) ? (1.0f - lt) : 1.0f;
            float wr = (j == 0) ? lr : (j == 1) ? (1.0f - lr) : 1.0f;
            ssum += T0s[v * K + k] * wt * wr;
        }
        float lss = __logf(ssum);
        for (int v = 0; v < V; ++v) {
            float lt = lts[v * K + k], lr = lrs[v * K + k];
            float wt = (i == 0) ? lt : (i == 1) ? (1.0f - lt) : 1.0f;
            float wr = (j == 0) ? lr : (j == 1) ? (1.0f - lr) : 1.0f;
            LT[(ij * V + v) * K + k] = __logf(T0s[v * K + k] * wt * wr) - lss;
        }
    }

    // LH[ij][enc][k]
    for (int id = tid; id < NIJ * ENC * K; id += 256) {
        const int k = id % K;
        const int enc = (id / K) % ENC;
        const int ij = id / (K * ENC);
        const int i = ij / 3, j = ij % 3;
        const int e2 = enc / 4, n2 = (enc / 2) % 2, c2 = enc % 2;
        float qt = (i == 0) ? pt[k] : (i == 1) ? (1.0f - pt[k]) : 1.0f;
        float qr = (j == 0) ? pr[k] : (j == 1) ? (1.0f - pr[k]) : 1.0f;
        LH[id] = __logf(qt * qr * pes[e2 * K + k] * pns[n2 * K + k] * pcs[c2 * K + k]);
    }

    // LM[ij][b] = log(mr3[ij, index[b]]), mr3 row = (i==2), col = (j==2)
    for (int id = tid; id < NIJ * B; id += 256) {
        const int ij = id >> 8, b = id & 255;
        const int sel = ((ij / 3 == 2) ? 2 : 0) + ((ij % 3 == 2) ? 1 : 0);
        LM[id] = __logf(mr[sel * D + index[b]]);
    }
}

// ---------------------------------------------------------------------------
// 3) Main streaming pass. One block per (ij,enc,b-chunk of 16). Pure float4
//    streaming of yphi; accumulates per-column sums over b in registers and
//    per-b slab sums via wave shuffles; epilogue dots with LT+LH and LM.
__global__ __launch_bounds__(256) void main_kernel(
    const float* __restrict__ yphi, const float* __restrict__ LT,
    const float* __restrict__ LH, const float* __restrict__ LM,
    double* __restrict__ acc) {
    const int blk = blockIdx.x;            // ijenc*NBC + bc
    const int tid = threadIdx.x;
    const int bc = blk % NBC;
    const int ijenc = blk / NBC;
    const int ij = ijenc / ENC;
    const int lane = tid & 63, wv = tid >> 6;
    const bool two = (tid < (VK / 4 - 256));   // 224 threads carry a 2nd column set

    __shared__ float Rw[4][BCH];
    __shared__ float wsum[4];

    const float4* __restrict__ yg =
        (const float4*)(yphi + (size_t)(ijenc * B + bc * BCH) * VK);

    float4 acc1 = make_float4(0.f, 0.f, 0.f, 0.f);
    float4 acc2 = make_float4(0.f, 0.f, 0.f, 0.f);
#pragma unroll 4
    for (int b = 0; b < BCH; ++b) {
        float4 y1 = yg[b * (VK / 4) + tid];
        float4 y2 = two ? yg[b * (VK / 4) + 256 + tid] : make_float4(0.f, 0.f, 0.f, 0.f);
        acc1.x += y1.x; acc1.y += y1.y; acc1.z += y1.z; acc1.w += y1.w;
        acc2.x += y2.x; acc2.y += y2.y; acc2.z += y2.z; acc2.w += y2.w;
        float tb = y1.x + y1.y + y1.z + y1.w + y2.x + y2.y + y2.z + y2.w;
#pragma unroll
        for (int off = 32; off; off >>= 1) tb += __shfl_down(tb, off, 64);
        if (lane == 0) Rw[wv][b] = tb;       // each wave owns its row
    }

    // Dot per-column sums with weights w(col) = LT[ij,col] + LH[ijenc, col%K]
    const int c1 = 4 * tid;
    float dot = 0.f;
    {
        float4 t4 = *(const float4*)&LT[ij * VK + c1];
        float4 h4 = *(const float4*)&LH[ijenc * K + (c1 % K)];   // 16B-aligned: (4t)%20 in {0,4,..,16}
        dot += acc1.x * (t4.x + h4.x) + acc1.y * (t4.y + h4.y)
             + acc1.z * (t4.z + h4.z) + acc1.w * (t4.w + h4.w);
    }
    if (two) {
        const int c2 = c1 + 1024;
        float4 t4 = *(const float4*)&LT[ij * VK + c2];
        float4 h4 = *(const float4*)&LH[ijenc * K + (c2 % K)];
        dot += acc2.x * (t4.x + h4.x) + acc2.y * (t4.y + h4.y)
             + acc2.z * (t4.z + h4.z) + acc2.w * (t4.w + h4.w);
    }
#pragma unroll
    for (int off = 32; off; off >>= 1) dot += __shfl_down(dot, off, 64);
    if (lane == 0) wsum[wv] = dot;
    __syncthreads();

    // b-dependent part: r_b * LM[ij,b]; lanes 16..63 contribute 0
    float v = 0.f;
    if (wv == 0 && lane < BCH) {
        float r = Rw[0][lane] + Rw[1][lane] + Rw[2][lane] + Rw[3][lane];
        v = r * LM[ij * B + bc * BCH + lane];
    }
    if (wv == 0) {
#pragma unroll
        for (int off = 8; off; off >>= 1) v += __shfl_down(v, off, 64);
        if (lane == 0) {
            float tot = wsum[0] + wsum[1] + wsum[2] + wsum[3] + v;
            atomicAdd(&acc[blk & (NSLOTS - 1)], (double)tot);
        }
    }
}

// ---------------------------------------------------------------------------
// 4) fold slots -> scalar output: out = -(sum) / (V*K)
__global__ void final_kernel(const double* __restrict__ acc, float* __restrict__ out) {
    __shared__ double sh[NSLOTS];
    const int tid = threadIdx.x;
    sh[tid] = acc[tid];
    __syncthreads();
    for (int off = NSLOTS / 2; off; off >>= 1) {
        if (tid < off) sh[tid] += sh[tid + off];
        __syncthreads();
    }
    if (tid == 0) out[0] = (float)(-sh[0] / (double)VK);
}

// ---------------------------------------------------------------------------
extern "C" void kernel_launch(void* const* d_in, const int* in_sizes, int n_in,
                              void* d_out, int out_size, void* d_ws, size_t ws_size,
                              hipStream_t stream) {
    const float* yphi = (const float*)d_in[0];
    const float* Y    = (const float*)d_in[1];
    const float* T0_  = (const float*)d_in[2];
    const float* t_   = (const float*)d_in[3];
    const float* r_   = (const float*)d_in[4];
    const float* e_   = (const float*)d_in[5];
    const float* n_   = (const float*)d_in[6];
    const float* c_   = (const float*)d_in[7];
    const int* index  = (const int*)d_in[8];
    float* out = (float*)d_out;

    char* ws = (char*)d_ws;
    double* acc = (double*)ws;                 // 256*8    = 2048 B
    float* mr   = (float*)(ws + 2048);         // 4096*4   = 16384 B  -> 18432
    float* LT   = (float*)(ws + 18432);        // 17280*4  = 69120 B  -> 87552
    float* LH   = (float*)(ws + 87552);        // 2880*4   = 11520 B  -> 99072
    float* LM   = (float*)(ws + 99072);        // 2304*4   = 9216 B   -> 108288

    hipLaunchKernelGGL(ymr_kernel, dim3(D), dim3(128), 0, stream, Y, mr, acc);
    hipLaunchKernelGGL(factors_kernel, dim3(1), dim3(256), 0, stream,
                       T0_, t_, r_, e_, n_, c_, mr, index, LT, LH, LM);
    hipLaunchKernelGGL(main_kernel, dim3(NIJ * ENC * NBC), dim3(256), 0, stream,
                       yphi, LT, LH, LM, acc);
    hipLaunchKernelGGL(final_kernel, dim3(1), dim3(NSLOTS), 0, stream, acc, out);
}

// Round 3
// 481.250 us; speedup vs baseline: 1.0013x; 1.0013x over previous
//
#include <hip/hip_runtime.h>

// Problem constants (from reference)
constexpr int V = 96, K = 20, D = 1024, B = 256;
constexpr int E_DIM = 4, N_DIM = 2, C_DIM = 2;
constexpr int VK = V * K;                  // 1920 floats per (i,j,e,n,c,b) slab
constexpr int ENC = E_DIM * N_DIM * C_DIM; // 16
constexpr int NIJ = 9;
constexpr int BCH = 16;                    // b-samples per main-pass block
constexpr int NBC = B / BCH;               // 16
constexpr int NSLOTS = 256;                // fp64 accumulator slots

// ---------------------------------------------------------------------------
// 1) Fused Y reduction + missing-rate. One 256-thread block per d.
//    Block 0 also zeroes the fp64 accumulator slots (stream-ordered before
//    any atomic accumulation in main_kernel).
__global__ __launch_bounds__(256) void ymr_kernel(const float* __restrict__ Y,
                                                  float* __restrict__ mr,
                                                  double* __restrict__ acc) {
    const int d = blockIdx.x;
    const int tid = threadIdx.x;
    if (d == 0) acc[tid] = 0.0;

    const float4* __restrict__ base = (const float4*)Y;
    float a[NIJ];
#pragma unroll
    for (int ij = 0; ij < NIJ; ++ij) {
        // 384 float4 per (ij,d): enc-major, 24 float4 per 96-float v-row
        int enc = tid / 24, v4 = tid % 24;
        float4 y = base[((size_t)(ij * ENC + enc) * D + d) * 24 + v4];
        float s = (y.x + y.y) + (y.z + y.w);
        if (tid < 128) {
            int idx = tid + 256;           // [256,384)
            enc = idx / 24; v4 = idx % 24;
            float4 z = base[((size_t)(ij * ENC + enc) * D + d) * 24 + v4];
            s += (z.x + z.y) + (z.z + z.w);
        }
        a[ij] = s;
    }
    __shared__ float Rw[4][NIJ];
    const int lane = tid & 63, wv = tid >> 6;
#pragma unroll
    for (int ij = 0; ij < NIJ; ++ij) {
        float s = a[ij];
#pragma unroll
        for (int off = 32; off; off >>= 1) s += __shfl_down(s, off, 64);
        if (lane == 0) Rw[wv][ij] = s;
    }
    __syncthreads();
    if (tid == 0) {
        float y[NIJ], tot = 0.f;
#pragma unroll
        for (int ij = 0; ij < NIJ; ++ij) {
            y[ij] = ((Rw[0][ij] + Rw[1][ij]) + (Rw[2][ij] + Rw[3][ij]));
            tot += y[ij];
        }
        mr[0 * D + d] = (y[0] + y[1] + y[3] + y[4]) / tot;  // m00
        mr[1 * D + d] = (y[2] + y[5]) / tot;                // m01 (r missing)
        mr[2 * D + d] = (y[6] + y[7]) / tot;                // m10 (t missing)
        mr[3 * D + d] = y[8] / tot;                         // m11
    }
}

// ---------------------------------------------------------------------------
// 2) Factor tables in LOG domain:
//    LT[ij][v][k]   = log(T[ij,v,k])                  (9*1920)
//    LH[ij][enc][k] = log(qt*qr*pe*pn*pc)             (9*16*20)
//    LM[ij][b]      = log(mr3[i,j, index[b]])         (9*256)
__global__ __launch_bounds__(256) void factors_kernel(
    const float* __restrict__ T0_, const float* __restrict__ t_,
    const float* __restrict__ r_, const float* __restrict__ e_,
    const float* __restrict__ n_, const float* __restrict__ c_,
    const float* __restrict__ mr, const int* __restrict__ index,
    float* __restrict__ LT, float* __restrict__ LH, float* __restrict__ LM) {
    __shared__ float T0s[VK], lts[VK], lrs[VK];
    __shared__ float pt[K], pr[K];
    __shared__ float pes[E_DIM * K], pns[N_DIM * K], pcs[C_DIM * K];
    const int tid = threadIdx.x;

    for (int idx = tid; idx < VK; idx += 256) {
        lts[idx] = 1.0f / (1.0f + expf(-t_[idx]));
        lrs[idx] = 1.0f / (1.0f + expf(-r_[idx]));
    }
    if (tid < K) {  // T0 = softmax(_T0, axis=0) per column k
        const int k = tid;
        float mx = -1e30f;
        for (int v = 0; v < V; ++v) mx = fmaxf(mx, T0_[v * K + k]);
        float ssum = 0.f;
        for (int v = 0; v < V; ++v) {
            float ev = expf(T0_[v * K + k] - mx);
            T0s[v * K + k] = ev; ssum += ev;
        }
        for (int v = 0; v < V; ++v) T0s[v * K + k] /= ssum;
    }
    __syncthreads();

    if (tid < K) {
        const int k = tid;
        float spt = 0.f, spr = 0.f;
        for (int v = 0; v < V; ++v) {
            spt += T0s[v * K + k] * lts[v * K + k];
            spr += T0s[v * K + k] * lrs[v * K + k];
        }
        pt[k] = spt; pr[k] = spr;
        {   // pe: softmax over E_DIM=4
            float m = -1e30f;
            for (int e2 = 0; e2 < E_DIM; ++e2) m = fmaxf(m, e_[e2 * K + k]);
            float se = 0.f; float tmp[E_DIM];
            for (int e2 = 0; e2 < E_DIM; ++e2) { tmp[e2] = expf(e_[e2 * K + k] - m); se += tmp[e2]; }
            for (int e2 = 0; e2 < E_DIM; ++e2) pes[e2 * K + k] = tmp[e2] / se;
        }
        {   // pn
            float m = fmaxf(n_[k], n_[K + k]);
            float a0 = expf(n_[k] - m), a1 = expf(n_[K + k] - m);
            pns[k] = a0 / (a0 + a1); pns[K + k] = a1 / (a0 + a1);
        }
        {   // pc
            float m = fmaxf(c_[k], c_[K + k]);
            float a0 = expf(c_[k] - m), a1 = expf(c_[K + k] - m);
            pcs[k] = a0 / (a0 + a1); pcs[K + k] = a1 / (a0 + a1);
        }
    }
    __syncthreads();

    // LT[ij][v][k]
    for (int id = tid; id < NIJ * K; id += 256) {
        const int k = id % K;
        const int ij = id / K;
        const int i = ij / 3, j = ij % 3;
        float ssum = 0.f;
        for (int v = 0; v < V; ++v) {
            float lt = lts[v * K + k], lr = lrs[v * K + k];
            float wt = (i == 0) ? lt : (i == 1) ? (1.0f - lt) : 1.0f;
            float wr = (j == 0) ? lr : (j == 1) ? (1.0f - lr) : 1.0f;
            ssum += T0s[v * K + k] * wt * wr;
        }
        float lss = __logf(ssum);
        for (int v = 0; v < V; ++v) {
            float lt = lts[v * K + k], lr = lrs[v * K + k];
            float wt = (i == 0) ? lt : (i == 1) ? (1.0f - lt) : 1.0f;
            float wr = (j == 0) ? lr : (j == 1) ? (1.0f - lr) : 1.0f;
            LT[(ij * V + v) * K + k] = __logf(T0s[v * K + k] * wt * wr) - lss;
        }
    }

    // LH[ij][enc][k]
    for (int id = tid; id < NIJ * ENC * K; id += 256) {
        const int k = id % K;
        const int enc = (id / K) % ENC;
        const int ij = id / (K * ENC);
        const int i = ij / 3, j = ij % 3;
        const int e2 = enc / 4, n2 = (enc / 2) % 2, c2 = enc % 2;
        float qt = (i == 0) ? pt[k] : (i == 1) ? (1.0f - pt[k]) : 1.0f;
        float qr = (j == 0) ? pr[k] : (j == 1) ? (1.0f - pr[k]) : 1.0f;
        LH[id] = __logf(qt * qr * pes[e2 * K + k] * pns[n2 * K + k] * pcs[c2 * K + k]);
    }

    // LM[ij][b]; mr3 row = (i==2), col = (j==2)
    for (int id = tid; id < NIJ * B; id += 256) {
        const int ij = id >> 8, b = id & 255;
        const int sel = ((ij / 3 == 2) ? 2 : 0) + ((ij % 3 == 2) ? 1 : 0);
        LM[id] = __logf(mr[sel * D + index[b]]);
    }
}

// ---------------------------------------------------------------------------
// 3) Main streaming pass. One block per (ij,enc,b-chunk of 16). Pure float4
//    streaming: per-column accumulators + an LM-weighted scalar accumulator
//    (Σ_b slabsum_b·LM_b == Σ_col Σ_b y[b,col]·LM_b), so NO cross-lane ops in
//    the hot loop. Single shuffle-reduce at block end.
__global__ __launch_bounds__(256) void main_kernel(
    const float* __restrict__ yphi, const float* __restrict__ LT,
    const float* __restrict__ LH, const float* __restrict__ LM,
    double* __restrict__ acc) {
    const int blk = blockIdx.x;            // ijenc*NBC + bc
    const int tid = threadIdx.x;
    const int bc = blk % NBC;
    const int ijenc = blk / NBC;
    const int ij = ijenc / ENC;
    const int lane = tid & 63, wv = tid >> 6;
    const bool two = (tid < (VK / 4 - 256));   // 224 threads carry a 2nd column set

    __shared__ float wsum[4];

    const float4* __restrict__ yg =
        (const float4*)(yphi + (size_t)(ijenc * B + bc * BCH) * VK);
    const float* __restrict__ lmp = LM + ij * B + bc * BCH;

    float4 a1 = make_float4(0.f, 0.f, 0.f, 0.f);
    float4 a2 = make_float4(0.f, 0.f, 0.f, 0.f);
    float wa = 0.f;
#pragma unroll 4
    for (int b = 0; b < BCH; ++b) {
        float lm = lmp[b];                              // block-uniform scalar
        float4 y1 = yg[b * (VK / 4) + tid];
        float4 y2 = two ? yg[b * (VK / 4) + 256 + tid]
                        : make_float4(0.f, 0.f, 0.f, 0.f);
        a1.x += y1.x; a1.y += y1.y; a1.z += y1.z; a1.w += y1.w;
        a2.x += y2.x; a2.y += y2.y; a2.z += y2.z; a2.w += y2.w;
        float t = ((y1.x + y1.y) + (y1.z + y1.w)) + ((y2.x + y2.y) + (y2.z + y2.w));
        wa = fmaf(lm, t, wa);
    }

    // Dot per-column sums with w(col) = LT[ij,col] + LH[ijenc, col%K]
    const int c1 = 4 * tid;
    float dot = wa;
    {
        float4 t4 = *(const float4*)&LT[ij * VK + c1];
        float4 h4 = *(const float4*)&LH[ijenc * K + (c1 % K)];   // 16B-aligned
        dot += a1.x * (t4.x + h4.x) + a1.y * (t4.y + h4.y)
             + a1.z * (t4.z + h4.z) + a1.w * (t4.w + h4.w);
    }
    if (two) {
        const int c2 = c1 + 1024;
        float4 t4 = *(const float4*)&LT[ij * VK + c2];
        float4 h4 = *(const float4*)&LH[ijenc * K + (c2 % K)];   // (c2)%20 ∈ {0,4,..}: aligned
        dot += a2.x * (t4.x + h4.x) + a2.y * (t4.y + h4.y)
             + a2.z * (t4.z + h4.z) + a2.w * (t4.w + h4.w);
    }
#pragma unroll
    for (int off = 32; off; off >>= 1) dot += __shfl_down(dot, off, 64);
    if (lane == 0) wsum[wv] = dot;
    __syncthreads();
    if (tid == 0) {
        float tot = (wsum[0] + wsum[1]) + (wsum[2] + wsum[3]);
        atomicAdd(&acc[blk & (NSLOTS - 1)], (double)tot);
    }
}

// ---------------------------------------------------------------------------
// 4) fold slots -> scalar output: out = -(sum) / (V*K)
__global__ void final_kernel(const double* __restrict__ acc, float* __restrict__ out) {
    __shared__ double sh[NSLOTS];
    const int tid = threadIdx.x;
    sh[tid] = acc[tid];
    __syncthreads();
    for (int off = NSLOTS / 2; off; off >>= 1) {
        if (tid < off) sh[tid] += sh[tid + off];
        __syncthreads();
    }
    if (tid == 0) out[0] = (float)(-sh[0] / (double)VK);
}

// ---------------------------------------------------------------------------
extern "C" void kernel_launch(void* const* d_in, const int* in_sizes, int n_in,
                              void* d_out, int out_size, void* d_ws, size_t ws_size,
                              hipStream_t stream) {
    const float* yphi = (const float*)d_in[0];
    const float* Y    = (const float*)d_in[1];
    const float* T0_  = (const float*)d_in[2];
    const float* t_   = (const float*)d_in[3];
    const float* r_   = (const float*)d_in[4];
    const float* e_   = (const float*)d_in[5];
    const float* n_   = (const float*)d_in[6];
    const float* c_   = (const float*)d_in[7];
    const int* index  = (const int*)d_in[8];
    float* out = (float*)d_out;

    char* ws = (char*)d_ws;
    double* acc = (double*)ws;                 // 256*8    = 2048 B
    float* mr   = (float*)(ws + 2048);         // 4096*4   = 16384 B  -> 18432
    float* LT   = (float*)(ws + 18432);        // 17280*4  = 69120 B  -> 87552
    float* LH   = (float*)(ws + 87552);        // 2880*4   = 11520 B  -> 99072
    float* LM   = (float*)(ws + 99072);        // 2304*4   = 9216 B   -> 108288

    hipLaunchKernelGGL(ymr_kernel, dim3(D), dim3(256), 0, stream, Y, mr, acc);
    hipLaunchKernelGGL(factors_kernel, dim3(1), dim3(256), 0, stream,
                       T0_, t_, r_, e_, n_, c_, mr, index, LT, LH, LM);
    hipLaunchKernelGGL(main_kernel, dim3(NIJ * ENC * NBC), dim3(256), 0, stream,
                       yphi, LT, LH, LM, acc);
    hipLaunchKernelGGL(final_kernel, dim3(1), dim3(NSLOTS), 0, stream, acc, out);
}